// Round 2
// baseline (511.543 us; speedup 1.0000x reference)
//
#include <hip/hip_runtime.h>
#include <cstdint>
#include <cstddef>

// ---------------- types / helpers ----------------
typedef __attribute__((ext_vector_type(4))) float f32x4;
typedef __attribute__((ext_vector_type(8))) unsigned short u16x8;
typedef __attribute__((ext_vector_type(4))) unsigned short u16x4;
typedef __bf16 bf16x8 __attribute__((ext_vector_type(8)));

__device__ __forceinline__ unsigned short f2bf(float f) {
  unsigned u = __builtin_bit_cast(unsigned, f);
  u += 0x7FFF + ((u >> 16) & 1);            // round-to-nearest-even
  return (unsigned short)(u >> 16);
}

__device__ __forceinline__ void mfma16x16x32(f32x4& acc, u16x8 a, u16x8 b) {
  acc = __builtin_amdgcn_mfma_f32_16x16x32_bf16(
      __builtin_bit_cast(bf16x8, a), __builtin_bit_cast(bf16x8, b), acc, 0, 0, 0);
}

typedef __attribute__((address_space(1))) const unsigned int as1_u32;
typedef __attribute__((address_space(3))) unsigned int as3_u32;
__device__ __forceinline__ void load_lds16(const void* g, void* l) {
  __builtin_amdgcn_global_load_lds((as1_u32*)g, (as3_u32*)l, 16, 0, 0);
}

// log2(e)/sqrt(128): folded into Q so attention exp is a bare v_exp_f32
#define QSCALE2 0.12751745f

// ---------------- kernel 1: rope table ----------------
__global__ void k_sincos(float2* __restrict__ tab) {
  int i = blockIdx.x * blockDim.x + threadIdx.x;
  if (i >= 2048 * 64) return;
  int t = i >> 6, f = i & 63;
  float inv = expf(-(float)f * 0.14391156831212787f);  // 10000^(-f/64)
  float ang = (float)t * inv;
  tab[i] = make_float2(cosf(ang), sinf(ang));
}

// ---------------- kernel 2: fused f32 -> bf16 converts (1 launch) ----------------
// ranges in float4 units: hs 1048576 | wq 4194304 | wk 524288 | wv 524288 | wo 4194304
__global__ void k_cvt_all(const float* __restrict__ hs, const float* __restrict__ wq,
                          const float* __restrict__ wk, const float* __restrict__ wv,
                          const float* __restrict__ wo,
                          unsigned short* __restrict__ hs_bf, unsigned short* __restrict__ w_bf) {
  const int total = 10485760;
  int stride = gridDim.x * blockDim.x;
  for (int i = blockIdx.x * blockDim.x + threadIdx.x; i < total; i += stride) {
    const float4* src;
    unsigned short* dst;
    long j;
    if (i < 1048576) { src = (const float4*)hs; j = i; dst = hs_bf + (size_t)i * 4; }
    else {
      int t = i - 1048576;
      dst = w_bf + (size_t)t * 4;              // q|k|v|o packed contiguously
      if (t < 4194304)      { src = (const float4*)wq; j = t; }
      else if (t < 4718592) { src = (const float4*)wk; j = t - 4194304; }
      else if (t < 5242880) { src = (const float4*)wv; j = t - 4718592; }
      else                  { src = (const float4*)wo; j = t - 5242880; }
    }
    float4 v = src[j];
    u16x4 o = { f2bf(v.x), f2bf(v.y), f2bf(v.z), f2bf(v.w) };
    *(u16x4*)dst = o;
  }
}

// ---------------- kernel 3: bf16 GEMM, C[M][N] = A[M][K] * Bt[N][K]^T ----------------
// 128x128 tile, BK=32, 4 waves, 2-phase LDS double-buffer: STAGE(next) issued
// BEFORE MFMA(cur); one __syncthreads per K-step (its vmcnt(0) drain lands after
// the MFMA phase covered the load latency). Low-occupancy (1.25 blk/CU) pipeline.
__global__ __launch_bounds__(256) void k_gemm_bt(
    const unsigned short* __restrict__ A, const unsigned short* __restrict__ Bt,
    float* __restrict__ C, int M, int N, int K) {
  __shared__ unsigned short lA[2][128 * 32];
  __shared__ unsigned short lB[2][128 * 32];
  const int tid = threadIdx.x;
  const int w = tid >> 6, lane = tid & 63;
  const int wm = w >> 1, wn = w & 1;
  const int m0 = blockIdx.y * 128, n0 = blockIdx.x * 128;
  const int lr = lane & 15, lg = lane >> 4;

  f32x4 acc[4][4];
#pragma unroll
  for (int i = 0; i < 4; i++)
#pragma unroll
    for (int j = 0; j < 4; j++) acc[i][j] = (f32x4){0.f, 0.f, 0.f, 0.f};

  const int srow = w * 32 + (lane >> 2);
  const int scol = (lane & 3) * 8;
  const unsigned short* gA = A + (size_t)(m0 + srow) * K + scol;
  const unsigned short* gB = Bt + (size_t)(n0 + srow) * K + scol;

  auto stage = [&](int buf, int kt) {
#pragma unroll
    for (int c = 0; c < 2; c++) {
      load_lds16(gA + (size_t)c * 16 * K + kt, &lA[buf][(w * 32 + c * 16) * 32]);
      load_lds16(gB + (size_t)c * 16 * K + kt, &lB[buf][(w * 32 + c * 16) * 32]);
    }
  };

  stage(0, 0);
  __syncthreads();                         // buf0 ready
  int cur = 0;
  for (int kt = 0; kt < K; kt += 32) {
    if (kt + 32 < K) stage(cur ^ 1, kt + 32);   // async prefetch, flies during MFMA
    u16x8 af[4], bf[4];
#pragma unroll
    for (int i = 0; i < 4; i++) af[i] = *(const u16x8*)&lA[cur][(wm * 64 + i * 16 + lr) * 32 + lg * 8];
#pragma unroll
    for (int j = 0; j < 4; j++) bf[j] = *(const u16x8*)&lB[cur][(wn * 64 + j * 16 + lr) * 32 + lg * 8];
#pragma unroll
    for (int i = 0; i < 4; i++)
#pragma unroll
      for (int j = 0; j < 4; j++) mfma16x16x32(acc[i][j], af[i], bf[j]);
    __syncthreads();                       // drains prefetch (vmcnt 0) + syncs waves
    cur ^= 1;
  }
#pragma unroll
  for (int i = 0; i < 4; i++)
#pragma unroll
    for (int j = 0; j < 4; j++)
#pragma unroll
      for (int r = 0; r < 4; r++) {
        int row = m0 + wm * 64 + i * 16 + lg * 4 + r;
        int col = n0 + wn * 64 + j * 16 + lr;
        C[(size_t)row * N + col] = acc[i][j][r];
      }
}

// ---------------- kernel 4: build K side of new_past + RoPE'd K cache ----------------
__global__ void k_build_k(const float* __restrict__ past, const float* __restrict__ qkv,
                          float* __restrict__ outk, unsigned short* __restrict__ kr,
                          const float2* __restrict__ tab) {
  int idx = blockIdx.x * blockDim.x + threadIdx.x;
  if (idx >= 4 * 2048 * 64) return;
  int d0 = idx & 63;
  int t = (idx >> 6) & 2047;
  int h = idx >> 17;
  float v1, v2;
  if (t < 1024) {
    const float* p = past + ((size_t)h * 1024 + t) * 128;
    v1 = p[d0]; v2 = p[d0 + 64];
  } else {
    const float* p = qkv + (size_t)(t - 1024) * 5120 + 4096 + h * 128;
    v1 = p[d0]; v2 = p[d0 + 64];
  }
  float* o = outk + ((size_t)h * 2048 + t) * 128;
  o[d0] = v1; o[d0 + 64] = v2;                       // new_past stores PRE-RoPE k
  float2 cs = tab[t * 64 + d0];
  unsigned short* ko = kr + ((size_t)h * 2048 + t) * 128;
  ko[d0]      = f2bf(v1 * cs.x - v2 * cs.y);
  ko[d0 + 64] = f2bf(v2 * cs.x + v1 * cs.y);
}

// ---------------- kernel 5: build V side of new_past + transposed V cache ----------------
__global__ void k_build_v(const float* __restrict__ past, const float* __restrict__ qkv,
                          float* __restrict__ outv, unsigned short* __restrict__ vt) {
  int idx = blockIdx.x * blockDim.x + threadIdx.x;
  if (idx >= 4 * 2048 * 128) return;
  int d = idx & 127;
  int t = (idx >> 7) & 2047;
  int h = idx >> 18;
  float val = (t < 1024) ? past[4 * 1024 * 128 + ((size_t)h * 1024 + t) * 128 + d]
                         : qkv[(size_t)(t - 1024) * 5120 + 4608 + h * 128 + d];
  outv[((size_t)h * 2048 + t) * 128 + d] = val;
  vt[((size_t)h * 128 + d) * 2048 + t] = f2bf(val);
}

// ---------------- kernel 6: RoPE q -> bf16, pre-scaled by log2(e)/sqrt(D) ----------------
__global__ void k_rope_q(const float* __restrict__ qkv, unsigned short* __restrict__ qr,
                         const float2* __restrict__ tab) {
  int idx = blockIdx.x * blockDim.x + threadIdx.x;
  if (idx >= 32 * 1024 * 64) return;
  int d0 = idx & 63;
  int q = (idx >> 6) & 1023;
  int h = idx >> 16;
  const float* p = qkv + (size_t)q * 5120 + h * 128;
  float v1 = p[d0], v2 = p[d0 + 64];
  float2 cs = tab[(1024 + q) * 64 + d0];
  unsigned short* o = qr + ((size_t)h * 1024 + q) * 128;
  o[d0]      = f2bf((v1 * cs.x - v2 * cs.y) * QSCALE2);
  o[d0 + 64] = f2bf((v2 * cs.x + v1 * cs.y) * QSCALE2);
}

// ---------------- kernel 7: flash attention, swapped-QK^T softmax ----------------
// mfma(K,Q) -> lane holds S^T[key=kb+16s+lg*4+r][query=lr]; in-lane max/sum over
// 8 keys + 2 shfl_xor(16,32); m/l/corr per-lane (query=lr). PV = mfma(V^T, P):
// acc[nt][r] = ctx[q0+lr][nt*16+lg*4+r] -> lane-local rescale, packed stores.
__global__ __launch_bounds__(64) void k_attn(
    const unsigned short* __restrict__ qr,  // [32][1024][128] (pre-scaled, log2 domain)
    const unsigned short* __restrict__ kr,  // [4][2048][128] (RoPE'd)
    const unsigned short* __restrict__ vt,  // [4][128][2048]
    unsigned short* __restrict__ ctxb) {    // [1024][4096] bf16
  __shared__ unsigned short plds[16 * 40];  // [query][key], 80B rows
  const int bid = blockIdx.x;
  const int h = bid >> 6;
  const int qt = bid & 63;
  const int q0 = qt * 16;
  const int kvh = h >> 3;
  const int l = threadIdx.x;
  const int lr = l & 15, lg = l >> 4;

  u16x8 qf[4];
  {
    const unsigned short* qb = qr + ((size_t)(h * 1024 + q0 + lr)) * 128 + lg * 8;
#pragma unroll
    for (int ks = 0; ks < 4; ks++) qf[ks] = *(const u16x8*)(qb + ks * 32);
  }
  f32x4 acc[8];
#pragma unroll
  for (int i = 0; i < 8; i++) acc[i] = (f32x4){0.f, 0.f, 0.f, 0.f};
  float m_r = -1e30f, l_r = 0.f;

  const int limit = 1024 + q0 + lr;         // this lane's query position
  const int ntiles = (1024 + q0 + 15) / 32 + 1;
  const unsigned short* kh = kr + (size_t)kvh * 2048 * 128;
  const unsigned short* vh = vt + (size_t)kvh * 128 * 2048;

  for (int t = 0; t < ntiles; t++) {
    const int kb = t * 32;
    f32x4 s[2];
#pragma unroll
    for (int sub = 0; sub < 2; sub++) {
      f32x4 a = (f32x4){0.f, 0.f, 0.f, 0.f};
      const unsigned short* kp = kh + (size_t)(kb + sub * 16 + lr) * 128 + lg * 8;
#pragma unroll
      for (int ks = 0; ks < 4; ks++) {
        u16x8 kf = *(const u16x8*)(kp + ks * 32);
        mfma16x16x32(a, kf, qf[ks]);        // A=K, B=Q -> S^T
      }
      s[sub] = a;
    }
    // per-lane: 8 score values (log2 domain), keys kb+16s+lg*4+r, query lr
    float v[8];
#pragma unroll
    for (int r = 0; r < 4; r++) { v[r] = s[0][r]; v[4 + r] = s[1][r]; }
    if (kb + 31 > 1024 + q0) {              // diagonal tiles only: causal mask
      const int kbase = kb + lg * 4;
#pragma unroll
      for (int r = 0; r < 4; r++) {
        if (kbase + r > limit)      v[r]     = -1e30f;
        if (kbase + 16 + r > limit) v[4 + r] = -1e30f;
      }
    }
    float tmax = v[0];
#pragma unroll
    for (int j = 1; j < 8; j++) tmax = fmaxf(tmax, v[j]);
    tmax = fmaxf(tmax, __shfl_xor(tmax, 16));
    tmax = fmaxf(tmax, __shfl_xor(tmax, 32));
    if (!__all(tmax <= m_r + 11.5f)) {      // defer-max (T13): rescale rarely
      float mn = fmaxf(m_r, tmax);
      float corr = exp2f(m_r - mn);
      m_r = mn;
      l_r *= corr;
#pragma unroll
      for (int nt = 0; nt < 8; nt++)
#pragma unroll
        for (int r = 0; r < 4; r++) acc[nt][r] *= corr;
    }
    float p[8];
    float psum = 0.f;
#pragma unroll
    for (int j = 0; j < 8; j++) { p[j] = exp2f(v[j] - m_r); psum += p[j]; }
    psum += __shfl_xor(psum, 16);
    psum += __shfl_xor(psum, 32);
    l_r += psum;
    // pack p -> bf16 pairs (round-half-up), write P[query=lr][key] to LDS
    unsigned wds[4];
#pragma unroll
    for (int j = 0; j < 4; j++) {
      unsigned lo = __builtin_bit_cast(unsigned, p[2 * j]) + 0x8000u;
      unsigned hi = __builtin_bit_cast(unsigned, p[2 * j + 1]) + 0x8000u;
      wds[j] = (hi & 0xFFFF0000u) | (lo >> 16);
    }
    char* pb = (char*)plds + lr * 80 + lg * 8;
    *(uint2*)(pb)      = make_uint2(wds[0], wds[1]);   // keys lg*4..+3
    *(uint2*)(pb + 32) = make_uint2(wds[2], wds[3]);   // keys 16+lg*4..+3
    __syncthreads();
    u16x8 pf = *(const u16x8*)&plds[lr * 40 + lg * 8]; // P[q=lr][k=lg*8..+7]
#pragma unroll
    for (int nt = 0; nt < 8; nt++) {
      const unsigned short* vp = vh + (size_t)(nt * 16 + lr) * 2048 + kb + lg * 8;
      u16x8 vf = *(const u16x8*)vp;
      mfma16x16x32(acc[nt], vf, pf);        // A=V^T, B=P -> ctx^T tiles
    }
    __syncthreads();
  }
  // epilogue: acc[nt][r] = ctx[q0+lr][nt*16+lg*4+r]; l/m lane-local
  float inv = 1.0f / l_r;
  unsigned short* ob = ctxb + (size_t)(q0 + lr) * 4096 + h * 128 + lg * 4;
#pragma unroll
  for (int nt = 0; nt < 8; nt++) {
    u16x4 o = { f2bf(acc[nt][0] * inv), f2bf(acc[nt][1] * inv),
                f2bf(acc[nt][2] * inv), f2bf(acc[nt][3] * inv) };
    *(u16x4*)(ob + nt * 16) = o;
  }
}

// ---------------- launch ----------------
extern "C" void kernel_launch(void* const* d_in, const int* in_sizes, int n_in,
                              void* d_out, int out_size, void* d_ws, size_t ws_size,
                              hipStream_t stream) {
  (void)in_sizes; (void)n_in; (void)out_size; (void)ws_size;
  const float* hs   = (const float*)d_in[0];
  const float* past = (const float*)d_in[1];
  // d_in[2] attention_mask: pure causal, synthesized analytically
  const float* Wq = (const float*)d_in[3];
  const float* Wk = (const float*)d_in[4];
  const float* Wv = (const float*)d_in[5];
  const float* Wo = (const float*)d_in[6];

  float* out_attn = (float*)d_out;                 // [1024][4096]
  float* out_pk = out_attn + 4194304;              // [4][2048][128]
  float* out_pv = out_pk + 1048576;                // [4][2048][128]

  char* ws = (char*)d_ws;
  unsigned short* hs_bf   = (unsigned short*)(ws);                // 8 MB
  unsigned short* wqkv_bf = (unsigned short*)(ws + 8388608);      // 40 MB [5120][4096]
  unsigned short* wo_bf   = (unsigned short*)(ws + 50331648);     // 32 MB [4096][4096]
  float*          qkv     = (float*)(ws + 83886080);              // 20 MB [1024][5120]
  unsigned short* qr      = (unsigned short*)(ws + 104857600);    // 8 MB
  unsigned short* kr      = (unsigned short*)(ws + 113246208);    // 2 MB
  unsigned short* vt      = (unsigned short*)(ws + 115343360);    // 2 MB
  unsigned short* ctxb    = (unsigned short*)(ws + 117440512);    // 8 MB
  float2*         tab     = (float2*)(ws + 125829120);            // 1 MB

  k_sincos<<<512, 256, 0, stream>>>(tab);
  k_cvt_all<<<2048, 256, 0, stream>>>(hs, Wq, Wk, Wv, Wo, hs_bf, wqkv_bf);

  dim3 g1(5120 / 128, 1024 / 128);
  k_gemm_bt<<<g1, 256, 0, stream>>>(hs_bf, wqkv_bf, qkv, 1024, 5120, 4096);

  k_build_k<<<2048, 256, 0, stream>>>(past, qkv, out_pk, kr, tab);
  k_build_v<<<4096, 256, 0, stream>>>(past, qkv, out_pv, vt);
  k_rope_q<<<8192, 256, 0, stream>>>(qkv, qr, tab);

  k_attn<<<32 * 64, 64, 0, stream>>>(qr, kr, vt, ctxb);

  dim3 g2(4096 / 128, 1024 / 128);
  k_gemm_bt<<<g2, 256, 0, stream>>>(ctxb, wo_bf, out_attn, 1024, 4096, 4096);
}

// Round 3
// 484.730 us; speedup vs baseline: 1.0553x; 1.0553x over previous
//
#include <hip/hip_runtime.h>
#include <cstdint>
#include <cstddef>

// ---------------- types / helpers ----------------
typedef __attribute__((ext_vector_type(4))) float f32x4;
typedef __attribute__((ext_vector_type(8))) unsigned short u16x8;
typedef __attribute__((ext_vector_type(4))) unsigned short u16x4;
typedef __bf16 bf16x8 __attribute__((ext_vector_type(8)));

__device__ __forceinline__ unsigned short f2bf(float f) {
  unsigned u = __builtin_bit_cast(unsigned, f);
  u += 0x7FFF + ((u >> 16) & 1);            // round-to-nearest-even
  return (unsigned short)(u >> 16);
}

__device__ __forceinline__ void mfma16x16x32(f32x4& acc, u16x8 a, u16x8 b) {
  acc = __builtin_amdgcn_mfma_f32_16x16x32_bf16(
      __builtin_bit_cast(bf16x8, a), __builtin_bit_cast(bf16x8, b), acc, 0, 0, 0);
}

typedef __attribute__((address_space(1))) const unsigned int as1_u32;
typedef __attribute__((address_space(3))) unsigned int as3_u32;
__device__ __forceinline__ void load_lds16(const void* g, void* l) {
  __builtin_amdgcn_global_load_lds((as1_u32*)g, (as3_u32*)l, 16, 0, 0);
}

// log2(e)/sqrt(128): folded into Q so attention exp is a bare v_exp_f32
#define QSCALE2 0.12751745f

// ---------------- kernel 1: rope table ----------------
__global__ void k_sincos(float2* __restrict__ tab) {
  int i = blockIdx.x * blockDim.x + threadIdx.x;
  if (i >= 2048 * 64) return;
  int t = i >> 6, f = i & 63;
  float inv = expf(-(float)f * 0.14391156831212787f);  // 10000^(-f/64)
  float ang = (float)t * inv;
  tab[i] = make_float2(cosf(ang), sinf(ang));
}

// ---------------- kernel 2: fused f32 -> bf16 converts (1 launch) ----------------
__global__ void k_cvt_all(const float* __restrict__ hs, const float* __restrict__ wq,
                          const float* __restrict__ wk, const float* __restrict__ wv,
                          const float* __restrict__ wo,
                          unsigned short* __restrict__ hs_bf, unsigned short* __restrict__ w_bf) {
  const int total = 10485760;
  int stride = gridDim.x * blockDim.x;
  for (int i = blockIdx.x * blockDim.x + threadIdx.x; i < total; i += stride) {
    const float4* src;
    unsigned short* dst;
    long j;
    if (i < 1048576) { src = (const float4*)hs; j = i; dst = hs_bf + (size_t)i * 4; }
    else {
      int t = i - 1048576;
      dst = w_bf + (size_t)t * 4;              // q|k|v|o packed contiguously
      if (t < 4194304)      { src = (const float4*)wq; j = t; }
      else if (t < 4718592) { src = (const float4*)wk; j = t - 4194304; }
      else if (t < 5242880) { src = (const float4*)wv; j = t - 4718592; }
      else                  { src = (const float4*)wo; j = t - 5242880; }
    }
    float4 v = src[j];
    u16x4 o = { f2bf(v.x), f2bf(v.y), f2bf(v.z), f2bf(v.w) };
    *(u16x4*)dst = o;
  }
}

// ---------------- kernel 3: bf16 GEMM with split-K ----------------
// C_partial[z][M][N] = A[M][k0:k0+KC] * Bt[N][k0:k0+KC]^T, z = blockIdx.z.
// 128x128 tile, BK=32, 4 waves, double-buffered global_load_lds staging.
// Split-K=4 -> 4x the blocks -> ~3 resident blocks/CU (m114 implicit overlap).
__global__ __launch_bounds__(256) void k_gemm_bt(
    const unsigned short* __restrict__ A, const unsigned short* __restrict__ Bt,
    float* __restrict__ C, int M, int N, int K, int KC) {
  __shared__ unsigned short lA[2][128 * 32];
  __shared__ unsigned short lB[2][128 * 32];
  const int tid = threadIdx.x;
  const int w = tid >> 6, lane = tid & 63;
  const int wm = w >> 1, wn = w & 1;
  const int m0 = blockIdx.y * 128, n0 = blockIdx.x * 128;
  const int k0 = blockIdx.z * KC;
  const int lr = lane & 15, lg = lane >> 4;
  float* Cp = C + (size_t)blockIdx.z * M * N;

  f32x4 acc[4][4];
#pragma unroll
  for (int i = 0; i < 4; i++)
#pragma unroll
    for (int j = 0; j < 4; j++) acc[i][j] = (f32x4){0.f, 0.f, 0.f, 0.f};

  const int srow = w * 32 + (lane >> 2);
  const int scol = (lane & 3) * 8;
  const unsigned short* gA = A + (size_t)(m0 + srow) * K + scol;
  const unsigned short* gB = Bt + (size_t)(n0 + srow) * K + scol;

  auto stage = [&](int buf, int kt) {
#pragma unroll
    for (int c = 0; c < 2; c++) {
      load_lds16(gA + (size_t)c * 16 * K + kt, &lA[buf][(w * 32 + c * 16) * 32]);
      load_lds16(gB + (size_t)c * 16 * K + kt, &lB[buf][(w * 32 + c * 16) * 32]);
    }
  };

  stage(0, k0);
  __syncthreads();
  int cur = 0;
  for (int kt = k0; kt < k0 + KC; kt += 32) {
    if (kt + 32 < k0 + KC) stage(cur ^ 1, kt + 32);
    u16x8 af[4], bf[4];
#pragma unroll
    for (int i = 0; i < 4; i++) af[i] = *(const u16x8*)&lA[cur][(wm * 64 + i * 16 + lr) * 32 + lg * 8];
#pragma unroll
    for (int j = 0; j < 4; j++) bf[j] = *(const u16x8*)&lB[cur][(wn * 64 + j * 16 + lr) * 32 + lg * 8];
#pragma unroll
    for (int i = 0; i < 4; i++)
#pragma unroll
      for (int j = 0; j < 4; j++) mfma16x16x32(acc[i][j], af[i], bf[j]);
    __syncthreads();
    cur ^= 1;
  }
#pragma unroll
  for (int i = 0; i < 4; i++)
#pragma unroll
    for (int j = 0; j < 4; j++)
#pragma unroll
      for (int r = 0; r < 4; r++) {
        int row = m0 + wm * 64 + i * 16 + lg * 4 + r;
        int col = n0 + wn * 64 + j * 16 + lr;
        Cp[(size_t)row * N + col] = acc[i][j][r];
      }
}

// ---------------- kernel 4: split-K reduce (4 partials) ----------------
__global__ void k_reduce4(const float4* __restrict__ p, float4* __restrict__ out,
                          int n4, size_t stride4) {
  int stridet = gridDim.x * blockDim.x;
  for (int i = blockIdx.x * blockDim.x + threadIdx.x; i < n4; i += stridet) {
    float4 a = p[i], b = p[i + stride4], c = p[i + 2 * stride4], d = p[i + 3 * stride4];
    out[i] = make_float4((a.x + b.x) + (c.x + d.x), (a.y + b.y) + (c.y + d.y),
                         (a.z + b.z) + (c.z + d.z), (a.w + b.w) + (c.w + d.w));
  }
}

// ---------------- kernel 5: fused post-GEMM1 (K build | V build | Q rope) ----------
// idx ranges: [0, 524288) K-side; [524288, 1572864) V-side; [1572864, 3670016) Q rope.
// Block-aligned boundaries (multiples of 256).
__global__ void k_post(const float* __restrict__ past, const float* __restrict__ qkv,
                       float* __restrict__ outk, float* __restrict__ outv,
                       unsigned short* __restrict__ kr, unsigned short* __restrict__ vt,
                       unsigned short* __restrict__ qr, const float2* __restrict__ tab) {
  int idx = blockIdx.x * blockDim.x + threadIdx.x;
  if (idx < 524288) {
    // K: new_past (pre-RoPE) + RoPE'd bf16 cache
    int d0 = idx & 63;
    int t = (idx >> 6) & 2047;
    int h = idx >> 17;
    float v1, v2;
    if (t < 1024) {
      const float* p = past + ((size_t)h * 1024 + t) * 128;
      v1 = p[d0]; v2 = p[d0 + 64];
    } else {
      const float* p = qkv + (size_t)(t - 1024) * 5120 + 4096 + h * 128;
      v1 = p[d0]; v2 = p[d0 + 64];
    }
    float* o = outk + ((size_t)h * 2048 + t) * 128;
    o[d0] = v1; o[d0 + 64] = v2;
    float2 cs = tab[t * 64 + d0];
    unsigned short* ko = kr + ((size_t)h * 2048 + t) * 128;
    ko[d0]      = f2bf(v1 * cs.x - v2 * cs.y);
    ko[d0 + 64] = f2bf(v2 * cs.x + v1 * cs.y);
  } else if (idx < 1572864) {
    // V: new_past + transposed bf16 cache [4][128][2048]
    int i = idx - 524288;
    int d = i & 127;
    int t = (i >> 7) & 2047;
    int h = i >> 18;
    float val = (t < 1024) ? past[4 * 1024 * 128 + ((size_t)h * 1024 + t) * 128 + d]
                           : qkv[(size_t)(t - 1024) * 5120 + 4608 + h * 128 + d];
    outv[((size_t)h * 2048 + t) * 128 + d] = val;
    vt[((size_t)h * 128 + d) * 2048 + t] = f2bf(val);
  } else {
    // Q: RoPE, pre-scaled by log2(e)/sqrt(D), bf16 [32][1024][128]
    int i = idx - 1572864;
    int d0 = i & 63;
    int q = (i >> 6) & 1023;
    int h = i >> 16;
    const float* p = qkv + (size_t)q * 5120 + h * 128;
    float v1 = p[d0], v2 = p[d0 + 64];
    float2 cs = tab[(1024 + q) * 64 + d0];
    unsigned short* o = qr + ((size_t)h * 1024 + q) * 128;
    o[d0]      = f2bf((v1 * cs.x - v2 * cs.y) * QSCALE2);
    o[d0 + 64] = f2bf((v2 * cs.x + v1 * cs.y) * QSCALE2);
  }
}

// ---------------- kernel 6: flash attention, swapped-QK^T softmax ----------------
__global__ __launch_bounds__(64) void k_attn(
    const unsigned short* __restrict__ qr,  // [32][1024][128] (pre-scaled, log2 domain)
    const unsigned short* __restrict__ kr,  // [4][2048][128] (RoPE'd)
    const unsigned short* __restrict__ vt,  // [4][128][2048]
    unsigned short* __restrict__ ctxb) {    // [1024][4096] bf16
  __shared__ unsigned short plds[16 * 40];
  const int bid = blockIdx.x;
  const int h = bid >> 6;
  const int qt = bid & 63;
  const int q0 = qt * 16;
  const int kvh = h >> 3;
  const int l = threadIdx.x;
  const int lr = l & 15, lg = l >> 4;

  u16x8 qf[4];
  {
    const unsigned short* qb = qr + ((size_t)(h * 1024 + q0 + lr)) * 128 + lg * 8;
#pragma unroll
    for (int ks = 0; ks < 4; ks++) qf[ks] = *(const u16x8*)(qb + ks * 32);
  }
  f32x4 acc[8];
#pragma unroll
  for (int i = 0; i < 8; i++) acc[i] = (f32x4){0.f, 0.f, 0.f, 0.f};
  float m_r = -1e30f, l_r = 0.f;

  const int limit = 1024 + q0 + lr;
  const int ntiles = (1024 + q0 + 15) / 32 + 1;
  const unsigned short* kh = kr + (size_t)kvh * 2048 * 128;
  const unsigned short* vh = vt + (size_t)kvh * 128 * 2048;

  for (int t = 0; t < ntiles; t++) {
    const int kb = t * 32;
    f32x4 s[2];
#pragma unroll
    for (int sub = 0; sub < 2; sub++) {
      f32x4 a = (f32x4){0.f, 0.f, 0.f, 0.f};
      const unsigned short* kp = kh + (size_t)(kb + sub * 16 + lr) * 128 + lg * 8;
#pragma unroll
      for (int ks = 0; ks < 4; ks++) {
        u16x8 kf = *(const u16x8*)(kp + ks * 32);
        mfma16x16x32(a, kf, qf[ks]);        // A=K, B=Q -> S^T
      }
      s[sub] = a;
    }
    float v[8];
#pragma unroll
    for (int r = 0; r < 4; r++) { v[r] = s[0][r]; v[4 + r] = s[1][r]; }
    if (kb + 31 > 1024 + q0) {
      const int kbase = kb + lg * 4;
#pragma unroll
      for (int r = 0; r < 4; r++) {
        if (kbase + r > limit)      v[r]     = -1e30f;
        if (kbase + 16 + r > limit) v[4 + r] = -1e30f;
      }
    }
    float tmax = v[0];
#pragma unroll
    for (int j = 1; j < 8; j++) tmax = fmaxf(tmax, v[j]);
    tmax = fmaxf(tmax, __shfl_xor(tmax, 16));
    tmax = fmaxf(tmax, __shfl_xor(tmax, 32));
    if (!__all(tmax <= m_r + 11.5f)) {      // defer-max (T13)
      float mn = fmaxf(m_r, tmax);
      float corr = exp2f(m_r - mn);
      m_r = mn;
      l_r *= corr;
#pragma unroll
      for (int nt = 0; nt < 8; nt++)
#pragma unroll
        for (int r = 0; r < 4; r++) acc[nt][r] *= corr;
    }
    float p[8];
    float psum = 0.f;
#pragma unroll
    for (int j = 0; j < 8; j++) { p[j] = exp2f(v[j] - m_r); psum += p[j]; }
    psum += __shfl_xor(psum, 16);
    psum += __shfl_xor(psum, 32);
    l_r += psum;
    unsigned wds[4];
#pragma unroll
    for (int j = 0; j < 4; j++) {
      unsigned lo = __builtin_bit_cast(unsigned, p[2 * j]) + 0x8000u;
      unsigned hi = __builtin_bit_cast(unsigned, p[2 * j + 1]) + 0x8000u;
      wds[j] = (hi & 0xFFFF0000u) | (lo >> 16);
    }
    char* pb = (char*)plds + lr * 80 + lg * 8;
    *(uint2*)(pb)      = make_uint2(wds[0], wds[1]);
    *(uint2*)(pb + 32) = make_uint2(wds[2], wds[3]);
    __syncthreads();
    u16x8 pf = *(const u16x8*)&plds[lr * 40 + lg * 8];
#pragma unroll
    for (int nt = 0; nt < 8; nt++) {
      const unsigned short* vp = vh + (size_t)(nt * 16 + lr) * 2048 + kb + lg * 8;
      u16x8 vf = *(const u16x8*)vp;
      mfma16x16x32(acc[nt], vf, pf);        // A=V^T, B=P -> ctx^T
    }
    __syncthreads();
  }
  float inv = 1.0f / l_r;
  unsigned short* ob = ctxb + (size_t)(q0 + lr) * 4096 + h * 128 + lg * 4;
#pragma unroll
  for (int nt = 0; nt < 8; nt++) {
    u16x4 o = { f2bf(acc[nt][0] * inv), f2bf(acc[nt][1] * inv),
                f2bf(acc[nt][2] * inv), f2bf(acc[nt][3] * inv) };
    *(u16x4*)(ob + nt * 16) = o;
  }
}

// ---------------- launch ----------------
extern "C" void kernel_launch(void* const* d_in, const int* in_sizes, int n_in,
                              void* d_out, int out_size, void* d_ws, size_t ws_size,
                              hipStream_t stream) {
  (void)in_sizes; (void)n_in; (void)out_size; (void)ws_size;
  const float* hs   = (const float*)d_in[0];
  const float* past = (const float*)d_in[1];
  // d_in[2] attention_mask: pure causal, synthesized analytically
  const float* Wq = (const float*)d_in[3];
  const float* Wk = (const float*)d_in[4];
  const float* Wv = (const float*)d_in[5];
  const float* Wo = (const float*)d_in[6];

  float* out_attn = (float*)d_out;                 // [1024][4096]
  float* out_pk = out_attn + 4194304;              // [4][2048][128]
  float* out_pv = out_pk + 1048576;                // [4][2048][128]

  const size_t MB = 1048576;
  char* ws = (char*)d_ws;
  unsigned short* hs_bf   = (unsigned short*)(ws);              // 8 MB
  unsigned short* wqkv_bf = (unsigned short*)(ws + 8 * MB);     // 40 MB [5120][4096]
  unsigned short* wo_bf   = (unsigned short*)(ws + 48 * MB);    // 32 MB [4096][4096]
  float*          qkv     = (float*)(ws + 80 * MB);             // 20 MB [1024][5120]
  float2*         tab     = (float2*)(ws + 100 * MB);           // 1 MB
  unsigned short* kr      = (unsigned short*)(ws + 101 * MB);   // 2 MB
  unsigned short* vt      = (unsigned short*)(ws + 103 * MB);   // 2 MB
  unsigned short* qr      = (unsigned short*)(ws + 105 * MB);   // 8 MB
  unsigned short* ctxb    = (unsigned short*)(ws + 113 * MB);   // 8 MB
  float*          gp      = (float*)(ws + 128 * MB);            // 80 MB split-K partials

  k_sincos<<<512, 256, 0, stream>>>(tab);
  k_cvt_all<<<2048, 256, 0, stream>>>(hs, Wq, Wk, Wv, Wo, hs_bf, wqkv_bf);

  dim3 g1(5120 / 128, 1024 / 128, 4);              // split-K=4: 1280 blocks
  k_gemm_bt<<<g1, 256, 0, stream>>>(hs_bf, wqkv_bf, gp, 1024, 5120, 4096, 1024);
  k_reduce4<<<2048, 256, 0, stream>>>((const float4*)gp, (float4*)qkv, 1310720, 1310720);

  k_post<<<14336, 256, 0, stream>>>(past, qkv, out_pk, out_pv, kr, vt, qr, tab);

  k_attn<<<32 * 64, 64, 0, stream>>>(qr, kr, vt, ctxb);

  dim3 g2(4096 / 128, 1024 / 128, 4);              // split-K=4: 1024 blocks
  k_gemm_bt<<<g2, 256, 0, stream>>>(ctxb, wo_bf, gp, 1024, 4096, 4096, 1024);
  k_reduce4<<<2048, 256, 0, stream>>>((const float4*)gp, (float4*)out_attn, 1048576, 1048576);
}